// Round 2
// baseline (975.474 us; speedup 1.0000x reference)
//
#include <hip/hip_runtime.h>
#include <stdint.h>

// Problem constants (fixed by reference: x is (32, 4097, 768) fp32, TOPK=0.1)
#define Nn      32
#define ROWS    4097
#define HW      4096          // rows excluding cls
#define Dd      768
#define KK      409           // max(1, int(4096*0.1))
#define TILE_D  16            // columns per threshold block
#define NB      512           // histogram buckets on (abs_bits >> 22)
#define CAND_MAX 1024         // candidate cap per column (expected ~360)
#define NTHREADS 1024

__device__ __forceinline__ unsigned wave_sum_u32(unsigned v) {
#pragma unroll
    for (int s = 32; s > 0; s >>= 1) v += __shfl_xor(v, s, 64);
    return v;
}

// ---------------------------------------------------------------------------
// Kernel 1: per-column exact k-th largest |x| bit-pattern + tie index cutoff.
// One block handles 16 consecutive d-columns of one batch n.
// LDS: 32KB hist + 64KB candidates + small -> ~97KB, 1 block/CU, 16 waves.
// ---------------------------------------------------------------------------
__global__ __launch_bounds__(NTHREADS) void topk_thresh_kernel(
        const float* __restrict__ x,
        unsigned* __restrict__ g_thr,
        int* __restrict__ g_cut) {
    __shared__ unsigned hist[TILE_D][NB];
    __shared__ unsigned cand[TILE_D][CAND_MAX];
    __shared__ unsigned ccnt[TILE_D];
    __shared__ unsigned colBucket[TILE_D];
    __shared__ unsigned colKp[TILE_D];     // rank within bucket, 1-based
    __shared__ unsigned colGt[TILE_D];     // count in strictly-higher buckets

    const int t  = threadIdx.x;
    const int n  = blockIdx.y;
    const int d0 = blockIdx.x * TILE_D;
    const float* xin = x + (size_t)n * ROWS * Dd + Dd + d0;  // skip cls row

    // zero LDS
    for (int i = t; i < TILE_D * NB; i += NTHREADS) ((unsigned*)hist)[i] = 0u;
    if (t < TILE_D) ccnt[t] = 0u;
    __syncthreads();

    const int c4 = t & 3;     // which float4 of the 16-wide tile
    const int r0 = t >> 2;    // 0..255 row phase

    // ---- phase 1: histogram (coalesced float4 stream, unroll 4) ----
#pragma unroll
    for (int base = 0; base < HW; base += 1024) {
        const int hw = base + r0;
        float4 v0 = *(const float4*)(xin + (size_t)(hw      ) * Dd + 4 * c4);
        float4 v1 = *(const float4*)(xin + (size_t)(hw + 256) * Dd + 4 * c4);
        float4 v2 = *(const float4*)(xin + (size_t)(hw + 512) * Dd + 4 * c4);
        float4 v3 = *(const float4*)(xin + (size_t)(hw + 768) * Dd + 4 * c4);
        const float4 vs[4] = {v0, v1, v2, v3};
#pragma unroll
        for (int u = 0; u < 4; ++u) {
            const float* pf = (const float*)&vs[u];
#pragma unroll
            for (int j = 0; j < 4; ++j) {
                unsigned ab = __float_as_uint(pf[j]) & 0x7fffffffu;
                atomicAdd(&hist[4 * c4 + j][ab >> 22], 1u);
            }
        }
    }
    __syncthreads();

    // ---- phase 2: find bucket containing rank KK (descending scan) ----
    if (t < TILE_D) {
        unsigned cum = 0;
        int b = NB - 1;
        for (; b > 0; --b) {
            unsigned h = hist[t][b];
            if (cum + h >= KK) break;
            cum += h;
        }
        colBucket[t] = (unsigned)b;
        colGt[t]     = cum;
        colKp[t]     = KK - cum;
    }
    __syncthreads();

    // ---- phase 3: collect candidates of the selected bucket ----
#pragma unroll
    for (int base = 0; base < HW; base += 1024) {
        const int hw = base + r0;
        float4 v0 = *(const float4*)(xin + (size_t)(hw      ) * Dd + 4 * c4);
        float4 v1 = *(const float4*)(xin + (size_t)(hw + 256) * Dd + 4 * c4);
        float4 v2 = *(const float4*)(xin + (size_t)(hw + 512) * Dd + 4 * c4);
        float4 v3 = *(const float4*)(xin + (size_t)(hw + 768) * Dd + 4 * c4);
        const float4 vs[4] = {v0, v1, v2, v3};
#pragma unroll
        for (int u = 0; u < 4; ++u) {
            const float* pf = (const float*)&vs[u];
#pragma unroll
            for (int j = 0; j < 4; ++j) {
                const int c = 4 * c4 + j;
                unsigned ab = __float_as_uint(pf[j]) & 0x7fffffffu;
                if ((ab >> 22) == colBucket[c]) {
                    unsigned p = atomicAdd(&ccnt[c], 1u);
                    if (p < CAND_MAX) cand[c][p] = ab;
                }
            }
        }
    }
    __syncthreads();

    // ---- phase 4: one wave per column — bisect exact threshold ----
    const int wave = t >> 6;
    const int lane = t & 63;
    const int c    = wave;  // 16 waves == 16 columns
    {
        unsigned cnt = ccnt[c];
        if (cnt > CAND_MAX) cnt = CAND_MAX;
        const unsigned kp = colKp[c];
        const unsigned b  = colBucket[c];
        unsigned lo = b << 22, hi = lo + (1u << 22);
        while (hi - lo > 1u) {
            const unsigned mid = lo + ((hi - lo) >> 1);
            unsigned cge = 0;
            for (unsigned j = lane; j < cnt; j += 64)
                cge += (cand[c][j] >= mid) ? 1u : 0u;
            cge = wave_sum_u32(cge);
            if (cge >= kp) lo = mid; else hi = mid;
        }
        const unsigned t_ = lo;  // exact KK-th largest abs bit pattern

        unsigned cge = 0, cgt = 0;
        for (unsigned j = lane; j < cnt; j += 64) {
            const unsigned v = cand[c][j];
            cge += (v >= t_) ? 1u : 0u;
            cgt += (v >  t_) ? 1u : 0u;
        }
        cge = wave_sum_u32(cge);
        cgt = wave_sum_u32(cgt);
        const unsigned eq   = cge - cgt;
        const unsigned need = KK - (colGt[c] + cgt);   // >= 1, <= eq

        int idxcut = HW - 1;   // default: keep all ties
        if (eq > need) {
            // rare: boundary tie collision -> find need-th smallest hw index.
            // Wave-local ballot compaction over a rescan of this column;
            // collected indices land in ascending hw order.
            unsigned base2 = 0;
            for (int it = 0; it < HW / 64; ++it) {
                const int hw = it * 64 + lane;
                unsigned ab2 = __float_as_uint(xin[(size_t)hw * Dd + c]) & 0x7fffffffu;
                const bool pred = (ab2 == t_);
                const unsigned long long m = __ballot(pred);
                if (pred) {
                    unsigned below = __popcll(m & ((1ull << lane) - 1ull));
                    cand[c][base2 + below] = (unsigned)hw;
                }
                base2 += (unsigned)__popcll(m);
            }
            __threadfence_block();
            idxcut = (int)cand[c][need - 1];
        }

        if (lane == 0) {
            g_thr[n * Dd + d0 + c] = t_;
            g_cut[n * Dd + d0 + c] = idxcut;
        }
    }
}

// ---------------------------------------------------------------------------
// Kernel 2: streaming masked copy (float4), cls row passes through.
// keep iff ab > thr  ||  (ab == thr && hw <= idxcut)
// ---------------------------------------------------------------------------
__global__ void topk_mask_kernel(const float* __restrict__ x,
                                 float* __restrict__ out,
                                 const unsigned* __restrict__ thr,
                                 const int* __restrict__ cut) {
    const int n = blockIdx.y;
    const int j = blockIdx.x * blockDim.x + threadIdx.x;   // float4 index in slab
    const int J = ROWS * (Dd / 4);                          // 786624
    if (j >= J) return;
    const size_t off = (size_t)n * ROWS * Dd + (size_t)j * 4;
    float4 v = *(const float4*)(x + off);
    const int row = j / (Dd / 4);
    if (row != 0) {
        const int hw = row - 1;
        const int d  = (j - row * (Dd / 4)) * 4;
        const uint4 tq = *(const uint4*)(thr + n * Dd + d);
        const int4  cq = *(const int4*)(cut + n * Dd + d);
        unsigned a;
        a = __float_as_uint(v.x) & 0x7fffffffu;
        if (!(a > tq.x || (a == tq.x && hw <= cq.x))) v.x = 0.0f;
        a = __float_as_uint(v.y) & 0x7fffffffu;
        if (!(a > tq.y || (a == tq.y && hw <= cq.y))) v.y = 0.0f;
        a = __float_as_uint(v.z) & 0x7fffffffu;
        if (!(a > tq.z || (a == tq.z && hw <= cq.z))) v.z = 0.0f;
        a = __float_as_uint(v.w) & 0x7fffffffu;
        if (!(a > tq.w || (a == tq.w && hw <= cq.w))) v.w = 0.0f;
    }
    *(float4*)(out + off) = v;
}

extern "C" void kernel_launch(void* const* d_in, const int* in_sizes, int n_in,
                              void* d_out, int out_size, void* d_ws, size_t ws_size,
                              hipStream_t stream) {
    const float* x = (const float*)d_in[0];
    float* out = (float*)d_out;
    // workspace layout: thr[32*768] u32, then cut[32*768] i32  (196,608 B total)
    unsigned* thr = (unsigned*)d_ws;
    int* cut = (int*)((char*)d_ws + (size_t)Nn * Dd * sizeof(unsigned));

    dim3 g1(Dd / TILE_D, Nn);   // 48 x 32
    topk_thresh_kernel<<<g1, NTHREADS, 0, stream>>>(x, thr, cut);

    dim3 g2((ROWS * (Dd / 4) + 255) / 256, Nn);  // 3073 x 32
    topk_mask_kernel<<<g2, 256, 0, stream>>>(x, out, thr, cut);
}